// Round 5
// baseline (750.949 us; speedup 1.0000x reference)
//
#include <hip/hip_runtime.h>
#include <hip/hip_bf16.h>
#include <math.h>

#define N_NODES 40000
#define N_EDGES 400000
#define N_GRAPH 64
#define IN_DIM 128
#define HD 256          // H*D
#define NCLS 10
#define SLOPE 0.2f

typedef __hip_bfloat16 bf16;
typedef __attribute__((ext_vector_type(8))) short short8;
typedef __attribute__((ext_vector_type(4))) float floatx4;

__device__ __forceinline__ float b2f(bf16 x){ return __bfloat162float(x); }
__device__ __forceinline__ bf16  f2b(float x){ return __float2bfloat16(x); }

// ------------------- per-tensor dtype probe: is this buffer fp32 or bf16? -------------------
__global__ __launch_bounds__(512) void probe_kernel(const ushort* __restrict__ w, int n, int* __restrict__ flag){
  __shared__ int cnt_s;
  int t = threadIdx.x;
  if (t == 0) cnt_s = 0;
  __syncthreads();
  int S = n >> 1; if (S > 512) S = 512;
  int bad = 0;
  if (t < S){
    ushort u = w[t*2];
    int e = (u >> 7) & 0xFF;
    if (e == 0xFF || e <= 0x60) bad = 1;
  }
  atomicAdd(&cnt_s, bad);
  __syncthreads();
  int thr = S >> 3; if (thr < 4) thr = 4;
  if (t == 0) *flag = (cnt_s >= thr) ? 1 : 0;    // 1 = fp32
}

// ------------------- convert/scrub: (fp32|bf16 per flag) -> clean bf16 -------------------
__global__ __launch_bounds__(256) void cvt_kernel(const void* __restrict__ src, bf16* __restrict__ dst,
                                                  int n, const int* __restrict__ flag){
  int i = blockIdx.x*256 + threadIdx.x;
  if (i >= n) return;
  float v;
  if (*flag) v = ((const float*)src)[i];
  else       v = b2f(((const bf16*)src)[i]);
  if (!isfinite(v)) v = 0.f;
  dst[i] = f2b(v);
}

// ------------------------- CSR build (by dst) -------------------------
__global__ __launch_bounds__(256) void hist_kernel(const int* __restrict__ dst, int* __restrict__ cnt){
  int i = blockIdx.x*256 + threadIdx.x;
  if (i < N_EDGES){ int d = dst[i]; if ((unsigned)d < N_NODES) atomicAdd(&cnt[d], 1); }
}

__global__ __launch_bounds__(1024) void scan_kernel(const int* __restrict__ cnt, int* __restrict__ rs, int* __restrict__ cur){
  __shared__ int s[1024];
  int t = threadIdx.x;
  const int CH = (N_NODES + 1023)/1024;
  int base = t*CH;
  int sum = 0;
  for (int i=0;i<CH;i++){ int idx=base+i; if (idx<N_NODES) sum += cnt[idx]; }
  s[t] = sum; __syncthreads();
  for (int off=1; off<1024; off<<=1){
    int v = (t>=off) ? s[t-off] : 0;
    __syncthreads();
    s[t] += v;
    __syncthreads();
  }
  int run = s[t] - sum;
  for (int i=0;i<CH;i++){ int idx=base+i; if (idx<N_NODES){ rs[idx]=run; cur[idx]=run; run+=cnt[idx]; } }
  if (t==1023) rs[N_NODES] = s[1023];
}

__global__ __launch_bounds__(256) void scatter_kernel(const int* __restrict__ src, const int* __restrict__ dst,
                                                      int* __restrict__ cur, int* __restrict__ csrc){
  int i = blockIdx.x*256 + threadIdx.x;
  if (i < N_EDGES){
    int d = dst[i];
    if ((unsigned)d >= N_NODES) return;
    int p = atomicAdd(&cur[d], 1);
    if ((unsigned)p < N_EDGES) csrc[p] = src[i];
  }
}

// ------------------------- GEMM: C[M,256] = A[M,K] @ B[K,256], bf16 in/out, f32 acc ----
__global__ __launch_bounds__(256) void gemm_kernel(const bf16* __restrict__ A, const bf16* __restrict__ B,
                                                   bf16* __restrict__ C, int K)
{
  __shared__ __align__(16) short As[64][48];
  __shared__ __align__(16) short Bs[64][48];   // Bs[col][k]
  int t = threadIdx.x;
  int lane = t & 63, w = t >> 6;
  int quad = lane >> 4, l15 = lane & 15;
  int bm = blockIdx.x, bn = blockIdx.y;
  int arow = t >> 2, ak = (t & 3) << 3;
  int bk = t >> 3, bn8 = (t & 7) << 3;
  const ushort* Au = (const ushort*)A;
  const ushort* Bu = (const ushort*)B;
  floatx4 acc[4] = {};
  for (int kc = 0; kc < K; kc += 32){
    short8 av = *(const short8*)(Au + (size_t)(bm*64 + arow)*K + kc + ak);
    short8 bv = *(const short8*)(Bu + (size_t)(kc + bk)*HD + bn*64 + bn8);
    __syncthreads();
    *(short8*)&As[arow][ak] = av;
    #pragma unroll
    for (int i=0;i<8;i++) Bs[bn8+i][bk] = bv[i];
    __syncthreads();
    short8 af = *(const short8*)&As[16*w + l15][8*quad];     // A[m=lane&15][k=quad*8+j]
    #pragma unroll
    for (int ct=0; ct<4; ++ct){
      short8 bfr = *(const short8*)&Bs[16*ct + l15][8*quad]; // B[k=quad*8+j][n=lane&15]
      acc[ct] = __builtin_amdgcn_mfma_f32_16x16x32_bf16(af, bfr, acc[ct], 0, 0, 0);
    }
  }
  #pragma unroll
  for (int ct=0; ct<4; ++ct){
    #pragma unroll
    for (int r=0; r<4; ++r){
      int row = bm*64 + 16*w + 4*quad + r;   // C/D: row=(lane>>4)*4+reg, col=lane&15
      int col = bn*64 + 16*ct + l15;
      C[(size_t)row*HD + col] = f2b(acc[ct][r]);
    }
  }
}

// ------------------------- el/er -------------------------
__global__ __launch_bounds__(256) void eler_kernel(const bf16* __restrict__ feat,
                                                   const bf16* __restrict__ al, const bf16* __restrict__ ar,
                                                   float* __restrict__ el, float* __restrict__ er)
{
  int n = blockIdx.x;
  int t = threadIdx.x;
  int h = t >> 6, d = t & 63;
  float f = b2f(feat[(size_t)n*HD + t]);
  float a = f * b2f(al[h*64 + d]);
  float b = f * b2f(ar[h*64 + d]);
  #pragma unroll
  for (int m=32; m; m>>=1){ a += __shfl_xor(a, m); b += __shfl_xor(b, m); }
  if (d == 0){ el[n*4+h] = a; er[n*4+h] = b; }
}

// ------------------------- per-dst aggregation (in-place on h_io) -------------------------
__global__ __launch_bounds__(256) void agg_kernel(const bf16* __restrict__ feat,
                                                  const float* __restrict__ el, const float* __restrict__ er,
                                                  const int* __restrict__ rs, const int* __restrict__ csrc,
                                                  bf16* __restrict__ h_io,
                                                  int residual, int activate)
{
  int n = blockIdx.x;
  int t = threadIdx.x;
  int h = t >> 6;
  float er_h = er[n*4 + h];
  int j0 = rs[n], j1 = rs[n+1];
  if (j0 < 0) j0 = 0;
  if (j1 > N_EDGES) j1 = N_EDGES;
  float res = residual ? b2f(h_io[(size_t)n*HD + t]) : 0.f;
  float acc = 0.f, den = 0.f;
  for (int j=j0; j<j1; ++j){
    int s = csrc[j];
    if ((unsigned)s >= N_NODES) continue;
    float e = el[s*4 + h] + er_h;
    e = (e > 0.f) ? e : SLOPE*e;                 // leaky_relu
    e = fminf(e, 30.f);                          // insurance
    float ee = __expf(e);                        // max-shift cancels in alpha
    den += ee;
    acc += ee * b2f(feat[(size_t)s*HD + t]);
  }
  float o = acc / fmaxf(den, 1e-9f) + res;
  if (activate) o = (o > 0.f) ? o : expm1f(o);   // elu
  h_io[(size_t)n*HD + t] = f2b(o);
}

// ------------------------- readout + classifier -------------------------
__global__ __launch_bounds__(64) void readout_kernel(const bf16* __restrict__ h2, const int* __restrict__ gid,
                                                     float* __restrict__ gacc, float* __restrict__ gcnt)
{
  int d = threadIdx.x;
  int n0 = blockIdx.x*64;
  float run = 0.f; int c = 0;
  int curg = gid[n0] & (N_GRAPH-1);
  for (int i=0;i<64;i++){
    int n = n0+i;
    int g = gid[n] & (N_GRAPH-1);
    const bf16* hp = h2 + (size_t)n*HD;
    float hm = 0.25f*( b2f(hp[d]) + b2f(hp[64+d]) + b2f(hp[128+d]) + b2f(hp[192+d]) );
    if (g != curg){
      atomicAdd(&gacc[curg*64+d], run);
      if (d==0) atomicAdd(&gcnt[curg], (float)c);
      run = 0.f; c = 0; curg = g;
    }
    run += hm; c++;
  }
  atomicAdd(&gacc[curg*64+d], run);
  if (d==0) atomicAdd(&gcnt[curg], (float)c);
}

// NOTE: output is FP32 (reference returns jnp.float32; harness contract: non-bf16 output -> float*)
__global__ __launch_bounds__(64) void classifier_kernel(const float* __restrict__ gacc, const float* __restrict__ gcnt,
                                                        const bf16* __restrict__ Wc, const bf16* __restrict__ bc,
                                                        float* __restrict__ out)
{
  int g = blockIdx.x, d = threadIdx.x;
  __shared__ float hg[64];
  hg[d] = gacc[g*64+d] / fmaxf(gcnt[g], 1.0f);
  __syncthreads();
  if (d < NCLS){
    float s = b2f(bc[d]);
    #pragma unroll
    for (int k=0;k<64;k++) s += hg[k] * b2f(Wc[k*NCLS + d]);
    out[g*NCLS + d] = s;
  }
}

// diagnostic: constant-fill output (fp32)
__global__ __launch_bounds__(64) void diag_kernel(float* __restrict__ out, float v){
  int i = blockIdx.x*64 + threadIdx.x;
  if (i < N_GRAPH*NCLS) out[i] = v;
}

// ------------------------- workspace layout (bytes) -------------------------
#define WS_NEEDED 54589216ull

extern "C" void kernel_launch(void* const* d_in, const int* in_sizes, int n_in,
                              void* d_out, int out_size, void* d_ws, size_t ws_size,
                              hipStream_t stream)
{
  (void)out_size;
  float* out = (float*)d_out;

  if (ws_size < WS_NEEDED){
    diag_kernel<<<10, 64, 0, stream>>>(out, (float)(ws_size >> 20));
    return;
  }

  // ---- input ordering check (confirmed dict order in R4; keep the guard) ----
  static const int sz_dict[15]  = {5120000,400000,400000,40000,32768,256,256,65536,256,256,65536,256,256,640,10};
  bool okd = (n_in >= 15);
  if (okd) for (int i=0;i<15;i++) if (in_sizes[i] != sz_dict[i]) { okd = false; break; }
  if (!okd){
    diag_kernel<<<10, 64, 0, stream>>>(out, 3.0f);
    return;
  }

  const void* p_x  = d_in[0];
  const int*  src  = (const int*)d_in[1];
  const int*  dst  = (const int*)d_in[2];
  const int*  gid  = (const int*)d_in[3];
  const void* p_W0 = d_in[4];
  const void* p_al0= d_in[5];
  const void* p_ar0= d_in[6];
  const void* p_W1 = d_in[7];
  const void* p_al1= d_in[8];
  const void* p_ar1= d_in[9];
  const void* p_W2 = d_in[10];
  const void* p_al2= d_in[11];
  const void* p_ar2= d_in[12];
  const void* p_Wc = d_in[13];
  const void* p_bc = d_in[14];

  char* ws = (char*)d_ws;
  int*   flags = (int*) (ws + 0);
  int*   rs   = (int*)  (ws + 256);
  int*   csrc = (int*)  (ws + 160512);
  float* el   = (float*)(ws + 1760512);
  float* er   = (float*)(ws + 2400512);
  int*   cnt  = (int*)  (ws + 1760512);   // aliases el (dead before eler)
  int*   cur  = (int*)  (ws + 2400512);   // aliases er (dead before eler)
  bf16*  H    = (bf16*) (ws + 3040512);
  bf16*  feat = (bf16*) (ws + 23520512);
  float* gacc = (float*)(ws + 44000512);
  float* gcnt = (float*)(ws + 44016896);
  bf16*  xc   = (bf16*) (ws + 44017152);
  bf16*  W0c  = (bf16*) (ws + 54257152);
  bf16*  W1c  = (bf16*) (ws + 54322688);
  bf16*  W2c  = (bf16*) (ws + 54453760);
  bf16*  al0c = (bf16*) (ws + 54584832);
  bf16*  ar0c = (bf16*) (ws + 54585344);
  bf16*  al1c = (bf16*) (ws + 54585856);
  bf16*  ar1c = (bf16*) (ws + 54586368);
  bf16*  al2c = (bf16*) (ws + 54586880);
  bf16*  ar2c = (bf16*) (ws + 54587392);
  bf16*  Wcc  = (bf16*) (ws + 54587904);
  bf16*  bcc  = (bf16*) (ws + 54589184);

  // ---- per-tensor dtype probe + convert to clean bf16 ----
  hipMemsetAsync(flags, 0, 256, stream);
  #define PRB(ptr, n, slot) probe_kernel<<<1, 512, 0, stream>>>((const ushort*)(ptr), (n), flags+(slot))
  PRB(p_x,   5120000, 0); PRB(p_W0, 32768, 1);
  PRB(p_al0, 256, 2);  PRB(p_ar0, 256, 3);
  PRB(p_W1,  65536, 4); PRB(p_al1, 256, 5); PRB(p_ar1, 256, 6);
  PRB(p_W2,  65536, 7); PRB(p_al2, 256, 8); PRB(p_ar2, 256, 9);
  PRB(p_Wc,  640, 10);
  #undef PRB
  #define CVT(srcp, dstp, n, slot) cvt_kernel<<<((n)+255)/256, 256, 0, stream>>>((srcp), (dstp), (n), flags+(slot))
  CVT(p_x,   xc,   5120000, 0); CVT(p_W0, W0c, 32768, 1);
  CVT(p_al0, al0c, 256, 2);  CVT(p_ar0, ar0c, 256, 3);
  CVT(p_W1,  W1c,  65536, 4); CVT(p_al1, al1c, 256, 5); CVT(p_ar1, ar1c, 256, 6);
  CVT(p_W2,  W2c,  65536, 7); CVT(p_al2, al2c, 256, 8); CVT(p_ar2, ar2c, 256, 9);
  CVT(p_Wc,  Wcc,  640, 10); CVT(p_bc, bcc, 10, 11);
  #undef CVT

  hipMemsetAsync(cnt, 0, N_NODES*sizeof(int), stream);
  hipMemsetAsync(gacc, 0, (N_GRAPH*64)*sizeof(float) + 256, stream);

  const int eb = (N_EDGES + 255)/256;
  hist_kernel   <<<eb, 256, 0, stream>>>(dst, cnt);
  scan_kernel   <<<1, 1024, 0, stream>>>(cnt, rs, cur);
  scatter_kernel<<<eb, 256, 0, stream>>>(src, dst, cur, csrc);

  // layer 0
  gemm_kernel<<<dim3(625,4), 256, 0, stream>>>(xc, W0c, feat, IN_DIM);
  eler_kernel<<<N_NODES, 256, 0, stream>>>(feat, al0c, ar0c, el, er);
  agg_kernel <<<N_NODES, 256, 0, stream>>>(feat, el, er, rs, csrc, H, 0, 1);
  // layer 1
  gemm_kernel<<<dim3(625,4), 256, 0, stream>>>(H, W1c, feat, HD);
  eler_kernel<<<N_NODES, 256, 0, stream>>>(feat, al1c, ar1c, el, er);
  agg_kernel <<<N_NODES, 256, 0, stream>>>(feat, el, er, rs, csrc, H, 1, 1);
  // layer 2
  gemm_kernel<<<dim3(625,4), 256, 0, stream>>>(H, W2c, feat, HD);
  eler_kernel<<<N_NODES, 256, 0, stream>>>(feat, al2c, ar2c, el, er);
  agg_kernel <<<N_NODES, 256, 0, stream>>>(feat, el, er, rs, csrc, H, 1, 0);
  // readout + classifier
  readout_kernel   <<<N_NODES/64, 64, 0, stream>>>(H, gid, gacc, gcnt);
  classifier_kernel<<<N_GRAPH, 64, 0, stream>>>(gacc, gcnt, Wcc, bcc, out);
}

// Round 6
// 460.550 us; speedup vs baseline: 1.6305x; 1.6305x over previous
//
#include <hip/hip_runtime.h>
#include <hip/hip_bf16.h>
#include <math.h>

#define N_NODES 40000
#define N_EDGES 400000
#define N_GRAPH 64
#define IN_DIM 128
#define HD 256          // H*D
#define NCLS 10
#define SLOPE 0.2f

typedef __hip_bfloat16 bf16;
typedef __attribute__((ext_vector_type(8))) short short8;
typedef __attribute__((ext_vector_type(4))) float floatx4;

__device__ __forceinline__ float b2f(bf16 x){ return __bfloat162float(x); }
__device__ __forceinline__ bf16  f2b(float x){ return __float2bfloat16(x); }

__device__ __forceinline__ floatx4 unpack4(uint2 u){
  floatx4 f;
  f[0] = __uint_as_float(u.x << 16);
  f[1] = __uint_as_float(u.x & 0xffff0000u);
  f[2] = __uint_as_float(u.y << 16);
  f[3] = __uint_as_float(u.y & 0xffff0000u);
  return f;
}

// ---------------- cvt: x fp32 -> bf16 (vectorized) ----------------
__global__ __launch_bounds__(256) void cvt_x_kernel(const float4* __restrict__ in, ushort* __restrict__ out){
  int i = blockIdx.x*256 + threadIdx.x;      // i < 1.28M
  if (i >= (N_NODES*IN_DIM)/4) return;
  float4 v = in[i];
  ushort4 o;
  o.x = __bfloat16_as_ushort(f2b(v.x));
  o.y = __bfloat16_as_ushort(f2b(v.y));
  o.z = __bfloat16_as_ushort(f2b(v.z));
  o.w = __bfloat16_as_ushort(f2b(v.w));
  *(ushort4*)(out + i*4) = o;
}

// ---------------- cvt W fp32 [K][256] -> chunk-packed bf16 Wt[K/64][256][64] ----------------
__global__ __launch_bounds__(256) void cvt_w_kernel(const float* __restrict__ W, ushort* __restrict__ Wt, int K){
  int e = blockIdx.x*256 + threadIdx.x;
  if (e >= K*HD) return;
  int k = e >> 8, n = e & 255;               // read coalesced over n
  float v = W[e];
  int idx = (((k>>6)*256 + n)<<6) + (k & 63);
  Wt[idx] = __bfloat16_as_ushort(f2b(v));
}

// ------------------------- CSR build (by dst) -------------------------
__global__ __launch_bounds__(256) void hist_kernel(const int* __restrict__ dst, int* __restrict__ cnt){
  int i = blockIdx.x*256 + threadIdx.x;
  if (i < N_EDGES) atomicAdd(&cnt[dst[i]], 1);
}

__global__ __launch_bounds__(1024) void scan_kernel(const int* __restrict__ cnt, int* __restrict__ rs, int* __restrict__ cur){
  __shared__ int s[1024];
  int t = threadIdx.x;
  const int CH = (N_NODES + 1023)/1024;
  int base = t*CH;
  int sum = 0;
  for (int i=0;i<CH;i++){ int idx=base+i; if (idx<N_NODES) sum += cnt[idx]; }
  s[t] = sum; __syncthreads();
  for (int off=1; off<1024; off<<=1){
    int v = (t>=off) ? s[t-off] : 0;
    __syncthreads();
    s[t] += v;
    __syncthreads();
  }
  int run = s[t] - sum;
  for (int i=0;i<CH;i++){ int idx=base+i; if (idx<N_NODES){ rs[idx]=run; cur[idx]=run; run+=cnt[idx]; } }
  if (t==1023) rs[N_NODES] = s[1023];
}

__global__ __launch_bounds__(256) void scatter_kernel(const int* __restrict__ src, const int* __restrict__ dst,
                                                      int* __restrict__ cur, int* __restrict__ csrc){
  int i = blockIdx.x*256 + threadIdx.x;
  if (i < N_EDGES){
    int p = atomicAdd(&cur[dst[i]], 1);
    csrc[p] = src[i];
  }
}

// ---------------- GEMM + fused el/er ----------------
// C[M,256] = A[M,K] @ W[K,256]; block = 64 rows x 256 cols; wave w = head/col-slab w.
// A-tile staged in LDS per 64-k chunk (shared by 4 waves); B-frags direct global from
// chunk-packed Wt (L2-resident). Epilogue: C store + el/er = C . al/ar (wave w == head w).
template<int K>
__global__ __launch_bounds__(256) void gemm_kernel(const bf16* __restrict__ A, const ushort* __restrict__ Wt,
                                                   bf16* __restrict__ C,
                                                   const float* __restrict__ al, const float* __restrict__ ar,
                                                   float* __restrict__ el, float* __restrict__ er)
{
  __shared__ __align__(16) short As[64][72];   // stride 36 dwords -> 2-way (free) on frag reads
  int t = threadIdx.x;
  int lane = t & 63, w = t >> 6;
  int quad = lane >> 4, l15 = lane & 15;
  int bm = blockIdx.x;
  const ushort* Au = (const ushort*)A;
  floatx4 acc[4][4] = {};                       // [mt][ct]
  int srow = t >> 3, scol = (t & 7) << 3;       // staging: rows srow, srow+32; 8 shorts each

  for (int kc = 0; kc < K/64; ++kc){
    __syncthreads();
    #pragma unroll
    for (int i=0;i<2;++i){
      int row = srow + 32*i;
      short8 v = *(const short8*)(Au + (size_t)(bm*64 + row)*K + kc*64 + scol);
      *(short8*)&As[row][scol] = v;
    }
    __syncthreads();
    #pragma unroll
    for (int j=0;j<2;++j){
      short8 af[4], bfr[4];
      #pragma unroll
      for (int mt=0;mt<4;++mt) af[mt] = *(const short8*)&As[16*mt + l15][8*quad + 32*j];
      #pragma unroll
      for (int ct=0;ct<4;++ct){
        int n = w*64 + 16*ct + l15;
        bfr[ct] = *(const short8*)(Wt + ((size_t)(kc*256 + n)<<6) + 8*quad + 32*j);
      }
      #pragma unroll
      for (int mt=0;mt<4;++mt)
        #pragma unroll
        for (int ct=0;ct<4;++ct)
          acc[mt][ct] = __builtin_amdgcn_mfma_f32_16x16x32_bf16(af[mt], bfr[ct], acc[mt][ct], 0, 0, 0);
    }
  }

  // epilogue: C store (C/D map: row=4*quad+r within 16-tile, col=l15)
  #pragma unroll
  for (int mt=0;mt<4;++mt)
    #pragma unroll
    for (int ct=0;ct<4;++ct)
      #pragma unroll
      for (int r=0;r<4;++r){
        int row = bm*64 + 16*mt + 4*quad + r;
        C[(size_t)row*HD + w*64 + 16*ct + l15] = f2b(acc[mt][ct][r]);
      }

  // fused el/er: head = w; cols of head w are exactly this wave's slab
  float alv[4], arv[4];
  #pragma unroll
  for (int ct=0;ct<4;++ct){ alv[ct] = al[w*64 + 16*ct + l15]; arv[ct] = ar[w*64 + 16*ct + l15]; }
  #pragma unroll
  for (int mt=0;mt<4;++mt)
    #pragma unroll
    for (int r=0;r<4;++r){
      float pe = 0.f, pr_ = 0.f;
      #pragma unroll
      for (int ct=0;ct<4;++ct){ float v = acc[mt][ct][r]; pe += v*alv[ct]; pr_ += v*arv[ct]; }
      #pragma unroll
      for (int m=1;m<16;m<<=1){ pe += __shfl_xor(pe, m); pr_ += __shfl_xor(pr_, m); }
      if (l15 == 0){
        int row = bm*64 + 16*mt + 4*quad + r;
        el[row*4 + w] = pe;
        er[row*4 + w] = pr_;
      }
    }
}

// ---------------- agg: wave-per-node, lane covers 4 cols, edge loop unrolled x2 ----------------
__global__ __launch_bounds__(256) void agg_kernel(const bf16* __restrict__ feat,
                                                  const float* __restrict__ el, const float* __restrict__ er,
                                                  const int* __restrict__ rs, const int* __restrict__ csrc,
                                                  bf16* __restrict__ h_io,
                                                  int residual, int activate)
{
  int t = threadIdx.x;
  int w = t >> 6, l = t & 63;
  int n = blockIdx.x*4 + w;
  int h = l >> 4;                       // head of cols 4l..4l+3
  float er_h = er[n*4 + h];
  int j0 = rs[n], j1 = rs[n+1];
  const uint2* fp = (const uint2*)feat; // row = 64 uint2
  uint2* hp = (uint2*)h_io;

  floatx4 res = {0,0,0,0};
  if (residual) res = unpack4(hp[(size_t)n*64 + l]);

  floatx4 acc0 = {0,0,0,0}, acc1 = {0,0,0,0};
  float den0 = 0.f, den1 = 0.f;
  int j = j0;
  for (; j+1 < j1; j += 2){
    int s0 = csrc[j], s1 = csrc[j+1];
    float e0 = el[s0*4+h] + er_h;
    float e1 = el[s1*4+h] + er_h;
    e0 = (e0 > 0.f) ? e0 : SLOPE*e0;
    e1 = (e1 > 0.f) ? e1 : SLOPE*e1;
    float ee0 = __expf(e0), ee1 = __expf(e1);
    floatx4 f0 = unpack4(fp[(size_t)s0*64 + l]);
    floatx4 f1 = unpack4(fp[(size_t)s1*64 + l]);
    den0 += ee0; den1 += ee1;
    #pragma unroll
    for (int k=0;k<4;++k){ acc0[k] += ee0*f0[k]; acc1[k] += ee1*f1[k]; }
  }
  if (j < j1){
    int s0 = csrc[j];
    float e0 = el[s0*4+h] + er_h;
    e0 = (e0 > 0.f) ? e0 : SLOPE*e0;
    float ee0 = __expf(e0);
    floatx4 f0 = unpack4(fp[(size_t)s0*64 + l]);
    den0 += ee0;
    #pragma unroll
    for (int k=0;k<4;++k) acc0[k] += ee0*f0[k];
  }
  float den = fmaxf(den0 + den1, 1e-9f);
  ushort4 o;
  #pragma unroll
  for (int k=0;k<4;++k){
    float v = (acc0[k] + acc1[k]) / den + res[k];
    if (activate) v = (v > 0.f) ? v : expm1f(v);
    ((ushort*)&o)[k] = __bfloat16_as_ushort(f2b(v));
  }
  *(ushort4*)&hp[(size_t)n*64 + l] = o;
}

// ---------------- readout: head-mean + per-graph segment sum ----------------
__global__ __launch_bounds__(256) void readout_kernel(const bf16* __restrict__ h2, const int* __restrict__ gid,
                                                      float* __restrict__ gacc, float* __restrict__ gcnt)
{
  int t = threadIdx.x;
  int w = t >> 6, l = t & 63;
  int nbase = blockIdx.x*64 + w*16;
  const uint2* hp = (const uint2*)h2;
  floatx4 run = {0,0,0,0};
  float c = 0.f;
  int curg = gid[nbase];
  for (int i=0;i<16;++i){
    int n = nbase + i;
    int g = gid[n];
    floatx4 v = unpack4(hp[(size_t)n*64 + l]);
    #pragma unroll
    for (int k=0;k<4;++k){ v[k] += __shfl_xor(v[k], 16); v[k] += __shfl_xor(v[k], 32); v[k] *= 0.25f; }
    if (g != curg){
      if (l < 16){
        #pragma unroll
        for (int k=0;k<4;++k) atomicAdd(&gacc[curg*64 + 4*l + k], run[k]);
        if (l == 0) atomicAdd(&gcnt[curg], c);
      }
      run = (floatx4){0,0,0,0}; c = 0.f; curg = g;
    }
    if (l < 16){
      #pragma unroll
      for (int k=0;k<4;++k) run[k] += v[k];
    }
    c += 1.f;
  }
  if (l < 16){
    #pragma unroll
    for (int k=0;k<4;++k) atomicAdd(&gacc[curg*64 + 4*l + k], run[k]);
    if (l == 0) atomicAdd(&gcnt[curg], c);
  }
}

__global__ __launch_bounds__(64) void classifier_kernel(const float* __restrict__ gacc, const float* __restrict__ gcnt,
                                                        const float* __restrict__ Wc, const float* __restrict__ bc,
                                                        float* __restrict__ out)
{
  int g = blockIdx.x, d = threadIdx.x;
  __shared__ float hg[64];
  hg[d] = gacc[g*64+d] / fmaxf(gcnt[g], 1.0f);
  __syncthreads();
  if (d < NCLS){
    float s = bc[d];
    #pragma unroll
    for (int k=0;k<64;k++) s += hg[k] * Wc[k*NCLS + d];
    out[g*NCLS + d] = s;
  }
}

__global__ __launch_bounds__(64) void diag_kernel(float* __restrict__ out, float v){
  int i = blockIdx.x*64 + threadIdx.x;
  if (i < N_GRAPH*NCLS) out[i] = v;
}

// ------------------------- workspace layout (bytes) -------------------------
//  rs    @ 256         : 160,256        cnt aliases el, cur aliases er (dead before gemm0)
//  csrc  @ 160,512     : 1,600,000
//  el    @ 1,760,512   : 640,000
//  er    @ 2,400,512   : 640,000
//  H     @ 3,040,512   : 20,480,000
//  feat  @ 23,520,512  : 20,480,000
//  gacc  @ 44,000,512  : 16,384 ; gcnt @ 44,016,896 : 256
//  xc    @ 44,017,152  : 10,240,000
//  Wt0   @ 54,257,152  : 65,536 ; Wt1 @ 54,322,688 : 131,072 ; Wt2 @ 54,453,760 : 131,072
#define WS_NEEDED 54589216ull

extern "C" void kernel_launch(void* const* d_in, const int* in_sizes, int n_in,
                              void* d_out, int out_size, void* d_ws, size_t ws_size,
                              hipStream_t stream)
{
  (void)out_size;
  float* out = (float*)d_out;

  if (ws_size < WS_NEEDED){
    diag_kernel<<<10, 64, 0, stream>>>(out, (float)(ws_size >> 20));
    return;
  }
  static const int sz_dict[15] = {5120000,400000,400000,40000,32768,256,256,65536,256,256,65536,256,256,640,10};
  bool okd = (n_in >= 15);
  if (okd) for (int i=0;i<15;i++) if (in_sizes[i] != sz_dict[i]) { okd = false; break; }
  if (!okd){ diag_kernel<<<10, 64, 0, stream>>>(out, 3.0f); return; }

  const float* x  = (const float*)d_in[0];
  const int* src  = (const int*)d_in[1];
  const int* dst  = (const int*)d_in[2];
  const int* gid  = (const int*)d_in[3];
  const float* W0 = (const float*)d_in[4];
  const float* al0= (const float*)d_in[5];
  const float* ar0= (const float*)d_in[6];
  const float* W1 = (const float*)d_in[7];
  const float* al1= (const float*)d_in[8];
  const float* ar1= (const float*)d_in[9];
  const float* W2 = (const float*)d_in[10];
  const float* al2= (const float*)d_in[11];
  const float* ar2= (const float*)d_in[12];
  const float* Wc = (const float*)d_in[13];
  const float* bc = (const float*)d_in[14];

  char* ws = (char*)d_ws;
  int*    rs   = (int*)   (ws + 256);
  int*    csrc = (int*)   (ws + 160512);
  float*  el   = (float*) (ws + 1760512);
  float*  er   = (float*) (ws + 2400512);
  int*    cnt  = (int*)   (ws + 1760512);   // aliases el (dead before gemm0 writes el)
  int*    cur  = (int*)   (ws + 2400512);   // aliases er (dead after scatter)
  bf16*   H    = (bf16*)  (ws + 3040512);
  bf16*   feat = (bf16*)  (ws + 23520512);
  float*  gacc = (float*) (ws + 44000512);
  float*  gcnt = (float*) (ws + 44016896);
  bf16*   xc   = (bf16*)  (ws + 44017152);
  ushort* Wt0  = (ushort*)(ws + 54257152);
  ushort* Wt1  = (ushort*)(ws + 54322688);
  ushort* Wt2  = (ushort*)(ws + 54453760);

  // prep: conversions
  cvt_x_kernel<<<(N_NODES*IN_DIM/4 + 255)/256, 256, 0, stream>>>((const float4*)x, (ushort*)xc);
  cvt_w_kernel<<<(IN_DIM*HD + 255)/256, 256, 0, stream>>>(W0, Wt0, IN_DIM);
  cvt_w_kernel<<<(HD*HD + 255)/256, 256, 0, stream>>>(W1, Wt1, HD);
  cvt_w_kernel<<<(HD*HD + 255)/256, 256, 0, stream>>>(W2, Wt2, HD);

  hipMemsetAsync(cnt, 0, N_NODES*sizeof(int), stream);
  hipMemsetAsync(gacc, 0, 16640, stream);   // gacc + gcnt

  const int eb = (N_EDGES + 255)/256;
  hist_kernel   <<<eb, 256, 0, stream>>>(dst, cnt);
  scan_kernel   <<<1, 1024, 0, stream>>>(cnt, rs, cur);
  scatter_kernel<<<eb, 256, 0, stream>>>(src, dst, cur, csrc);

  // layer 0: xc[N,128] -> feat (+el/er); agg -> H
  gemm_kernel<IN_DIM><<<625, 256, 0, stream>>>(xc, Wt0, feat, al0, ar0, el, er);
  agg_kernel<<<N_NODES/4, 256, 0, stream>>>(feat, el, er, rs, csrc, H, 0, 1);
  // layer 1: H -> feat (+el/er); agg in-place (residual)
  gemm_kernel<HD><<<625, 256, 0, stream>>>(H, Wt1, feat, al1, ar1, el, er);
  agg_kernel<<<N_NODES/4, 256, 0, stream>>>(feat, el, er, rs, csrc, H, 1, 1);
  // layer 2
  gemm_kernel<HD><<<625, 256, 0, stream>>>(H, Wt2, feat, al2, ar2, el, er);
  agg_kernel<<<N_NODES/4, 256, 0, stream>>>(feat, el, er, rs, csrc, H, 1, 0);
  // readout + classifier
  readout_kernel   <<<625, 256, 0, stream>>>(H, gid, gacc, gcnt);
  classifier_kernel<<<N_GRAPH, 64, 0, stream>>>(gacc, gcnt, Wc, bc, out);
}

// Round 8
// 357.818 us; speedup vs baseline: 2.0987x; 1.2871x over previous
//
#include <hip/hip_runtime.h>
#include <hip/hip_bf16.h>
#include <math.h>

#define N_NODES 40000
#define N_EDGES 400000
#define N_GRAPH 64
#define IN_DIM 128
#define HD 256          // H*D
#define NCLS 10
#define SLOPE 0.2f

typedef __hip_bfloat16 bf16;
typedef __attribute__((ext_vector_type(8))) short short8;
typedef __attribute__((ext_vector_type(4))) float floatx4;

__device__ __forceinline__ float b2f(bf16 x){ return __bfloat162float(x); }
__device__ __forceinline__ bf16  f2b(float x){ return __float2bfloat16(x); }

__device__ __forceinline__ floatx4 unpack4(uint2 u){
  floatx4 f;
  f[0] = __uint_as_float(u.x << 16);
  f[1] = __uint_as_float(u.x & 0xffff0000u);
  f[2] = __uint_as_float(u.y << 16);
  f[3] = __uint_as_float(u.y & 0xffff0000u);
  return f;
}

__device__ __forceinline__ int wave_incl_scan(int x, int lane){
  #pragma unroll
  for (int m=1;m<64;m<<=1){
    int v = __shfl_up(x, m);
    if (lane >= m) x += v;
  }
  return x;
}

// ---------------- cvt: x fp32 -> bf16 (vectorized) ----------------
__global__ __launch_bounds__(256) void cvt_x_kernel(const float4* __restrict__ in, ushort* __restrict__ out){
  int i = blockIdx.x*256 + threadIdx.x;
  if (i >= (N_NODES*IN_DIM)/4) return;
  float4 v = in[i];
  ushort4 o;
  o.x = __bfloat16_as_ushort(f2b(v.x));
  o.y = __bfloat16_as_ushort(f2b(v.y));
  o.z = __bfloat16_as_ushort(f2b(v.z));
  o.w = __bfloat16_as_ushort(f2b(v.w));
  *(ushort4*)(out + i*4) = o;
}

// ---------------- cvt W fp32 [K][256] -> chunk-packed bf16 Wt[K/64][256][64] ----------------
__global__ __launch_bounds__(256) void cvt_w_kernel(const float* __restrict__ W, ushort* __restrict__ Wt, int K){
  int e = blockIdx.x*256 + threadIdx.x;
  if (e >= K*HD) return;
  int k = e >> 8, n = e & 255;
  float v = W[e];
  int idx = (((k>>6)*256 + n)<<6) + (k & 63);
  Wt[idx] = __bfloat16_as_ushort(f2b(v));
}

// ------------------------- CSR build (by dst) -------------------------
__global__ __launch_bounds__(256) void hist_kernel(const int* __restrict__ dst, int* __restrict__ cnt){
  int i = blockIdx.x*256 + threadIdx.x;
  if (i < N_EDGES) atomicAdd(&cnt[dst[i]], 1);
}

// hierarchical exclusive scan of cnt[40000] -> rs/cur (3 kernels, all coalesced)
__global__ __launch_bounds__(1024) void reduce_kernel(const int* __restrict__ cnt, int* __restrict__ bsum){
  int t = threadIdx.x, b = blockIdx.x;
  int idx = b*1024 + t;
  int c = (idx < N_NODES) ? cnt[idx] : 0;
  #pragma unroll
  for (int m=32;m;m>>=1) c += __shfl_down(c, m);
  __shared__ int ws[16];
  int w = t>>6, l = t&63;
  if (l==0) ws[w] = c;
  __syncthreads();
  if (t==0){
    int s = 0;
    #pragma unroll
    for (int i=0;i<16;i++) s += ws[i];
    bsum[b] = s;
  }
}

__global__ __launch_bounds__(64) void scanb_kernel(const int* __restrict__ bsum, int* __restrict__ boff,
                                                   int* __restrict__ rs){
  int t = threadIdx.x;
  int v = (t < 40) ? bsum[t] : 0;
  int incl = wave_incl_scan(v, t);
  if (t < 40) boff[t] = incl - v;
  if (t == 39) rs[N_NODES] = incl;   // total = E
}

__global__ __launch_bounds__(1024) void csr_scan_kernel(const int* __restrict__ cnt, const int* __restrict__ boff,
                                                        int* __restrict__ rs, int* __restrict__ cur){
  int t = threadIdx.x, b = blockIdx.x;
  int idx = b*1024 + t;
  int c = (idx < N_NODES) ? cnt[idx] : 0;
  int w = t>>6, l = t&63;
  int wi = wave_incl_scan(c, l);
  __shared__ int ws[16];
  __shared__ int wexcl[16];
  if (l==63) ws[w] = wi;
  __syncthreads();
  if (t < 16){
    int x = ws[t];
    #pragma unroll
    for (int m=1;m<16;m<<=1){
      int v = __shfl_up(x, m);
      if (t >= m) x += v;
    }
    wexcl[t] = x - ws[t];
  }
  __syncthreads();
  if (idx < N_NODES){
    int p = boff[b] + wexcl[w] + wi - c;
    rs[idx] = p; cur[idx] = p;
  }
}

__global__ __launch_bounds__(256) void scatter_kernel(const int* __restrict__ src, const int* __restrict__ dst,
                                                      int* __restrict__ cur, int* __restrict__ csrc){
  int i = blockIdx.x*256 + threadIdx.x;
  if (i < N_EDGES){
    int p = atomicAdd(&cur[dst[i]], 1);
    csrc[p] = src[i];
  }
}

// ---------------- GEMM + fused el/er ----------------
template<int K>
__global__ __launch_bounds__(256) void gemm_kernel(const bf16* __restrict__ A, const ushort* __restrict__ Wt,
                                                   bf16* __restrict__ C,
                                                   const float* __restrict__ al, const float* __restrict__ ar,
                                                   float* __restrict__ el, float* __restrict__ er)
{
  __shared__ __align__(16) short As[64][72];
  int t = threadIdx.x;
  int lane = t & 63, w = t >> 6;
  int quad = lane >> 4, l15 = lane & 15;
  int bm = blockIdx.x;
  const ushort* Au = (const ushort*)A;
  floatx4 acc[4][4] = {};
  int srow = t >> 3, scol = (t & 7) << 3;

  for (int kc = 0; kc < K/64; ++kc){
    __syncthreads();
    #pragma unroll
    for (int i=0;i<2;++i){
      int row = srow + 32*i;
      short8 v = *(const short8*)(Au + (size_t)(bm*64 + row)*K + kc*64 + scol);
      *(short8*)&As[row][scol] = v;
    }
    __syncthreads();
    #pragma unroll
    for (int j=0;j<2;++j){
      short8 af[4], bfr[4];
      #pragma unroll
      for (int mt=0;mt<4;++mt) af[mt] = *(const short8*)&As[16*mt + l15][8*quad + 32*j];
      #pragma unroll
      for (int ct=0;ct<4;++ct){
        int n = w*64 + 16*ct + l15;
        bfr[ct] = *(const short8*)(Wt + ((size_t)(kc*256 + n)<<6) + 8*quad + 32*j);
      }
      #pragma unroll
      for (int mt=0;mt<4;++mt)
        #pragma unroll
        for (int ct=0;ct<4;++ct)
          acc[mt][ct] = __builtin_amdgcn_mfma_f32_16x16x32_bf16(af[mt], bfr[ct], acc[mt][ct], 0, 0, 0);
    }
  }

  #pragma unroll
  for (int mt=0;mt<4;++mt)
    #pragma unroll
    for (int ct=0;ct<4;++ct)
      #pragma unroll
      for (int r=0;r<4;++r){
        int row = bm*64 + 16*mt + 4*quad + r;
        C[(size_t)row*HD + w*64 + 16*ct + l15] = f2b(acc[mt][ct][r]);
      }

  float alv[4], arv[4];
  #pragma unroll
  for (int ct=0;ct<4;++ct){ alv[ct] = al[w*64 + 16*ct + l15]; arv[ct] = ar[w*64 + 16*ct + l15]; }
  #pragma unroll
  for (int mt=0;mt<4;++mt)
    #pragma unroll
    for (int r=0;r<4;++r){
      float pe = 0.f, pr_ = 0.f;
      #pragma unroll
      for (int ct=0;ct<4;++ct){ float v = acc[mt][ct][r]; pe += v*alv[ct]; pr_ += v*arv[ct]; }
      #pragma unroll
      for (int m=1;m<16;m<<=1){ pe += __shfl_xor(pe, m); pr_ += __shfl_xor(pr_, m); }
      if (l15 == 0){
        int row = bm*64 + 16*mt + 4*quad + r;
        el[row*4 + w] = pe;
        er[row*4 + w] = pr_;
      }
    }
}

// ---------------- agg: wave-per-node, lane covers 4 cols, edge loop unrolled x4 ----------------
__global__ __launch_bounds__(256) void agg_kernel(const bf16* __restrict__ feat,
                                                  const float* __restrict__ el, const float* __restrict__ er,
                                                  const int* __restrict__ rs, const int* __restrict__ csrc,
                                                  bf16* __restrict__ h_io,
                                                  int residual, int activate)
{
  int t = threadIdx.x;
  int w = t >> 6, l = t & 63;
  int n = blockIdx.x*4 + w;
  int h = l >> 4;
  float er_h = er[n*4 + h];
  int j0 = rs[n], j1 = rs[n+1];
  const uint2* fp = (const uint2*)feat;
  uint2* hp = (uint2*)h_io;

  floatx4 res = {0,0,0,0};
  if (residual) res = unpack4(hp[(size_t)n*64 + l]);

  floatx4 a0={0,0,0,0}, a1={0,0,0,0}, a2={0,0,0,0}, a3={0,0,0,0};
  float d0=0.f, d1=0.f, d2=0.f, d3=0.f;
  int j = j0;
  for (; j+3 < j1; j += 4){
    int s0 = csrc[j], s1 = csrc[j+1], s2 = csrc[j+2], s3 = csrc[j+3];
    float e0 = el[s0*4+h] + er_h;
    float e1 = el[s1*4+h] + er_h;
    float e2 = el[s2*4+h] + er_h;
    float e3 = el[s3*4+h] + er_h;
    e0 = (e0 > 0.f) ? e0 : SLOPE*e0;
    e1 = (e1 > 0.f) ? e1 : SLOPE*e1;
    e2 = (e2 > 0.f) ? e2 : SLOPE*e2;
    e3 = (e3 > 0.f) ? e3 : SLOPE*e3;
    float ee0 = __expf(e0), ee1 = __expf(e1), ee2 = __expf(e2), ee3 = __expf(e3);
    floatx4 f0 = unpack4(fp[(size_t)s0*64 + l]);
    floatx4 f1 = unpack4(fp[(size_t)s1*64 + l]);
    floatx4 f2 = unpack4(fp[(size_t)s2*64 + l]);
    floatx4 f3 = unpack4(fp[(size_t)s3*64 + l]);
    d0 += ee0; d1 += ee1; d2 += ee2; d3 += ee3;
    #pragma unroll
    for (int k=0;k<4;++k){
      a0[k] += ee0*f0[k]; a1[k] += ee1*f1[k];
      a2[k] += ee2*f2[k]; a3[k] += ee3*f3[k];
    }
  }
  for (; j < j1; ++j){
    int s0 = csrc[j];
    float e0 = el[s0*4+h] + er_h;
    e0 = (e0 > 0.f) ? e0 : SLOPE*e0;
    float ee0 = __expf(e0);
    floatx4 f0 = unpack4(fp[(size_t)s0*64 + l]);
    d0 += ee0;
    #pragma unroll
    for (int k=0;k<4;++k) a0[k] += ee0*f0[k];
  }
  float den = fmaxf((d0+d1)+(d2+d3), 1e-9f);
  ushort4 o;
  #pragma unroll
  for (int k=0;k<4;++k){
    float v = ((a0[k]+a1[k])+(a2[k]+a3[k])) / den + res[k];
    if (activate) v = (v > 0.f) ? v : expm1f(v);
    ((ushort*)&o)[k] = __bfloat16_as_ushort(f2b(v));
  }
  *(ushort4*)&hp[(size_t)n*64 + l] = o;
}

// ---------------- readout: head-mean + per-graph segment sum ----------------
__global__ __launch_bounds__(256) void readout_kernel(const bf16* __restrict__ h2, const int* __restrict__ gid,
                                                      float* __restrict__ gacc, float* __restrict__ gcnt)
{
  int t = threadIdx.x;
  int w = t >> 6, l = t & 63;
  int nbase = blockIdx.x*64 + w*16;
  const uint2* hp = (const uint2*)h2;
  floatx4 run = {0,0,0,0};
  float c = 0.f;
  int curg = gid[nbase];
  for (int i=0;i<16;++i){
    int n = nbase + i;
    int g = gid[n];
    floatx4 v = unpack4(hp[(size_t)n*64 + l]);
    #pragma unroll
    for (int k=0;k<4;++k){ v[k] += __shfl_xor(v[k], 16); v[k] += __shfl_xor(v[k], 32); v[k] *= 0.25f; }
    if (g != curg){
      if (l < 16){
        #pragma unroll
        for (int k=0;k<4;++k) atomicAdd(&gacc[curg*64 + 4*l + k], run[k]);
        if (l == 0) atomicAdd(&gcnt[curg], c);
      }
      run = (floatx4){0,0,0,0}; c = 0.f; curg = g;
    }
    if (l < 16){
      #pragma unroll
      for (int k=0;k<4;++k) run[k] += v[k];
    }
    c += 1.f;
  }
  if (l < 16){
    #pragma unroll
    for (int k=0;k<4;++k) atomicAdd(&gacc[curg*64 + 4*l + k], run[k]);
    if (l == 0) atomicAdd(&gcnt[curg], c);
  }
}

__global__ __launch_bounds__(64) void classifier_kernel(const float* __restrict__ gacc, const float* __restrict__ gcnt,
                                                        const float* __restrict__ Wc, const float* __restrict__ bc,
                                                        float* __restrict__ out)
{
  int g = blockIdx.x, d = threadIdx.x;
  __shared__ float hg[64];
  hg[d] = gacc[g*64+d] / fmaxf(gcnt[g], 1.0f);
  __syncthreads();
  if (d < NCLS){
    float s = bc[d];
    #pragma unroll
    for (int k=0;k<64;k++) s += hg[k] * Wc[k*NCLS + d];
    out[g*NCLS + d] = s;
  }
}

__global__ __launch_bounds__(64) void diag_kernel(float* __restrict__ out, float v){
  int i = blockIdx.x*64 + threadIdx.x;
  if (i < N_GRAPH*NCLS) out[i] = v;
}

// ------------------------- workspace layout (bytes) -------------------------
//  rs    @ 256         : 160,256
//  csrc  @ 160,512     : 1,600,000
//  el    @ 1,760,512   : 640,000  [cnt aliases; dead before gemm0]
//  er    @ 2,400,512   : 640,000  [cur aliases; dead after scatter]
//  H     @ 3,040,512   : 20,480,000
//  feat  @ 23,520,512  : 20,480,000
//  gacc  @ 44,000,512  : 16,384 ; gcnt @ 44,016,896 : 256
//  xc    @ 44,017,152  : 10,240,000
//  Wt0   @ 54,257,152  : 65,536 ; Wt1 @ 54,322,688 : 131,072 ; Wt2 @ 54,453,760 : 131,072
//  bsum  @ 54,584,832  : 256 ; boff @ 54,585,088 : 256
#define WS_NEEDED 54589216ull

extern "C" void kernel_launch(void* const* d_in, const int* in_sizes, int n_in,
                              void* d_out, int out_size, void* d_ws, size_t ws_size,
                              hipStream_t stream)
{
  (void)out_size;
  float* out = (float*)d_out;

  if (ws_size < WS_NEEDED){
    diag_kernel<<<10, 64, 0, stream>>>(out, (float)(ws_size >> 20));
    return;
  }
  static const int sz_dict[15] = {5120000,400000,400000,40000,32768,256,256,65536,256,256,65536,256,256,640,10};
  bool okd = (n_in >= 15);
  if (okd) for (int i=0;i<15;i++) if (in_sizes[i] != sz_dict[i]) { okd = false; break; }
  if (!okd){ diag_kernel<<<10, 64, 0, stream>>>(out, 3.0f); return; }

  const float* x  = (const float*)d_in[0];
  const int* src  = (const int*)d_in[1];
  const int* dst  = (const int*)d_in[2];
  const int* gid  = (const int*)d_in[3];
  const float* W0 = (const float*)d_in[4];
  const float* al0= (const float*)d_in[5];
  const float* ar0= (const float*)d_in[6];
  const float* W1 = (const float*)d_in[7];
  const float* al1= (const float*)d_in[8];
  const float* ar1= (const float*)d_in[9];
  const float* W2 = (const float*)d_in[10];
  const float* al2= (const float*)d_in[11];
  const float* ar2= (const float*)d_in[12];
  const float* Wc = (const float*)d_in[13];
  const float* bc = (const float*)d_in[14];

  char* ws = (char*)d_ws;
  int*    rs   = (int*)   (ws + 256);
  int*    csrc = (int*)   (ws + 160512);
  float*  el   = (float*) (ws + 1760512);
  float*  er   = (float*) (ws + 2400512);
  int*    cnt  = (int*)   (ws + 1760512);
  int*    cur  = (int*)   (ws + 2400512);
  bf16*   H    = (bf16*)  (ws + 3040512);
  bf16*   feat = (bf16*)  (ws + 23520512);
  float*  gacc = (float*) (ws + 44000512);
  float*  gcnt = (float*) (ws + 44016896);
  bf16*   xc   = (bf16*)  (ws + 44017152);
  ushort* Wt0  = (ushort*)(ws + 54257152);
  ushort* Wt1  = (ushort*)(ws + 54322688);
  ushort* Wt2  = (ushort*)(ws + 54453760);
  int*    bsum = (int*)   (ws + 54584832);
  int*    boff = (int*)   (ws + 54585088);

  // prep
  cvt_x_kernel<<<(N_NODES*IN_DIM/4 + 255)/256, 256, 0, stream>>>((const float4*)x, (ushort*)xc);
  cvt_w_kernel<<<(IN_DIM*HD + 255)/256, 256, 0, stream>>>(W0, Wt0, IN_DIM);
  cvt_w_kernel<<<(HD*HD + 255)/256, 256, 0, stream>>>(W1, Wt1, HD);
  cvt_w_kernel<<<(HD*HD + 255)/256, 256, 0, stream>>>(W2, Wt2, HD);

  hipMemsetAsync(cnt, 0, N_NODES*sizeof(int), stream);
  hipMemsetAsync(gacc, 0, 16640, stream);

  const int eb = (N_EDGES + 255)/256;
  const int sb = (N_NODES + 1023)/1024;   // 40
  hist_kernel    <<<eb, 256, 0, stream>>>(dst, cnt);
  reduce_kernel  <<<sb, 1024, 0, stream>>>(cnt, bsum);
  scanb_kernel   <<<1, 64, 0, stream>>>(bsum, boff, rs);
  csr_scan_kernel<<<sb, 1024, 0, stream>>>(cnt, boff, rs, cur);
  scatter_kernel <<<eb, 256, 0, stream>>>(src, dst, cur, csrc);

  // layer 0
  gemm_kernel<IN_DIM><<<625, 256, 0, stream>>>(xc, Wt0, feat, al0, ar0, el, er);
  agg_kernel<<<N_NODES/4, 256, 0, stream>>>(feat, el, er, rs, csrc, H, 0, 1);
  // layer 1
  gemm_kernel<HD><<<625, 256, 0, stream>>>(H, Wt1, feat, al1, ar1, el, er);
  agg_kernel<<<N_NODES/4, 256, 0, stream>>>(feat, el, er, rs, csrc, H, 1, 1);
  // layer 2
  gemm_kernel<HD><<<625, 256, 0, stream>>>(H, Wt2, feat, al2, ar2, el, er);
  agg_kernel<<<N_NODES/4, 256, 0, stream>>>(feat, el, er, rs, csrc, H, 1, 0);
  // readout + classifier
  readout_kernel   <<<625, 256, 0, stream>>>(H, gid, gacc, gcnt);
  classifier_kernel<<<N_GRAPH, 64, 0, stream>>>(gacc, gcnt, Wc, bc, out);
}